// Round 1
// baseline (229.921 us; speedup 1.0000x reference)
//
#include <hip/hip_runtime.h>

// PositionalEncoding: out[b,s,d] = x[b,s,d] + pe[s,d]
//   pe[s,d] = sin(s / 10000^((d/2)/S)) if d even else cos(...)
// x: [B=8, S=4096, D=1024] float32.
//
// R1 lesson: 8-batch *loop* per thread serialized memory ops (24 VGPRs ->
//   1 load in flight) -> 2.28 TB/s.
// R2 lesson: __builtin_nontemporal_* needs a clang ext_vector_type.
// R3 (this): pe[s,d] is batch-independent. Each thread owns one (s,d4)
//   slot for FOUR batches: sincos computed once (TRANS/byte /4), four
//   fully-unrolled independent NT loads in flight (4 KiB/wave vs 1 KiB),
//   NT loads since there is zero reuse. Streams at 16 MiB stride remain
//   perfectly coalesced per wave. Target: 4.4 -> ~6.3 TB/s kernel-only.

#define PE_S 4096
#define PE_D 1024
#define B4   (PE_S * PE_D / 4)      // 1,048,576 float4 per batch image (2^20)
#define NTHR (8 * B4 / 4)           // 2,097,152 threads, 4 batches each

typedef float f32x4 __attribute__((ext_vector_type(4)));

__global__ __launch_bounds__(256) void PositionalEncoding_84095459656362_kernel(
    const float* __restrict__ x, float* __restrict__ out) {
    const int i  = blockIdx.x * blockDim.x + threadIdx.x;
    const int p  = i & (B4 - 1);                 // float4 index within one batch image
    const int h  = i >> 20;                      // 0 -> batches 0..3, 1 -> batches 4..7
    const int d4 = (p & (PE_D / 4 - 1)) << 2;    // d base: 0..1020
    const int s  = p >> 8;                       // sequence pos 0..4095

    // angle(k) = s * 10000^(-k/S) = s * exp2(k * c), c = -log2(10000)/4096
    const float c  = -0.0032440703857f;
    const float r1 = 0.99775390625f;             // 10000^(-1/4096)
    const float e0 = __builtin_exp2f((float)(d4 >> 1) * c);
    const float a0 = (float)s * e0;
    const float a1 = a0 * r1;

    float s0, c0, s1, c1;
    __sincosf(a0, &s0, &c0);                     // d even -> sin, d odd -> cos
    __sincosf(a1, &s1, &c1);
    f32x4 pe;
    pe.x = s0; pe.y = c0; pe.z = s1; pe.w = c1;

    const f32x4* xin = (const f32x4*)x   + h * (4 * B4) + p;
    f32x4*       o   = (f32x4*)out       + h * (4 * B4) + p;

    // Four independent streaming loads in flight before any dependent use.
    const f32x4 v0 = __builtin_nontemporal_load(xin);
    const f32x4 v1 = __builtin_nontemporal_load(xin + B4);
    const f32x4 v2 = __builtin_nontemporal_load(xin + 2 * B4);
    const f32x4 v3 = __builtin_nontemporal_load(xin + 3 * B4);

    __builtin_nontemporal_store(v0 + pe, o);
    __builtin_nontemporal_store(v1 + pe, o + B4);
    __builtin_nontemporal_store(v2 + pe, o + 2 * B4);
    __builtin_nontemporal_store(v3 + pe, o + 3 * B4);
}

extern "C" void kernel_launch(void* const* d_in, const int* in_sizes, int n_in,
                              void* d_out, int out_size, void* d_ws, size_t ws_size,
                              hipStream_t stream) {
    const float* x = (const float*)d_in[0];
    float* out = (float*)d_out;
    PositionalEncoding_84095459656362_kernel<<<NTHR / 256, 256, 0, stream>>>(x, out);
}

// Round 3
// 220.102 us; speedup vs baseline: 1.0446x; 1.0446x over previous
//
#include <hip/hip_runtime.h>

// PositionalEncoding: out[b,s,d] = x[b,s,d] + pe[s,d]
//   pe[s,d] = sin(s / 10000^((d/2)/S)) if d even else cos(...)
// x: [B=8, S=4096, D=1024] float32.
//
// R1 lesson: 8-batch loop per thread serialized memory ops -> 2.28 TB/s.
// R2 lesson: __builtin_nontemporal_store needs a clang ext_vector_type.
// R3 lesson: 4-batch/thread (8 strided streams/wave + NT loads) regressed
//   (221.4 -> 229.9). Arithmetic: pe chain (~40 trans cyc) vs ~800 cyc BW
//   budget per wave-iteration -> ALU fully hidden; MLP ample (32 KiB/CU in
//   flight vs ~9 needed). Flat m13 pattern is correct; HBM efficiency is
//   what matters.
// R4: exact R2 structure, single change: plain cached store instead of NT
//   store (fills hit 6.6 TB/s with plain stores; A/B the NT flag).
// R5 (this): R4 never ran — container acquisition failed twice (infra).
//   Identical resubmission.

#define PE_S 4096
#define PE_D 1024
#define N4   (8 * PE_S * PE_D / 4)   // 8,388,608 float4 elements

typedef float f32x4 __attribute__((ext_vector_type(4)));

__global__ __launch_bounds__(256) void PositionalEncoding_84095459656362_kernel(
    const float* __restrict__ x, float* __restrict__ out) {
    const int i  = blockIdx.x * blockDim.x + threadIdx.x;   // float4 index
    const int d4 = (i & (PE_D / 4 - 1)) << 2;               // d base: 0..1020
    const int s  = (i >> 8) & (PE_S - 1);                   // sequence pos

    // angle(k) = s * 10000^(-k/S) = s * exp2(k * c), c = -log2(10000)/4096
    const float c   = -0.0032440703857f;
    const float r1  = 0.99775390625f;                        // 10000^(-1/4096)
    const float e0  = __builtin_exp2f((float)(d4 >> 1) * c);
    const float a0  = (float)s * e0;
    const float a1  = a0 * r1;

    float s0, c0, s1, c1;
    __sincosf(a0, &s0, &c0);   // d even -> sin, d odd -> cos
    __sincosf(a1, &s1, &c1);

    const f32x4 v = ((const f32x4*)x)[i];
    f32x4 r;
    r.x = v.x + s0;
    r.y = v.y + c0;
    r.z = v.z + s1;
    r.w = v.w + c1;
    ((f32x4*)out)[i] = r;      // plain cached store (A/B vs R2's NT store)
}

extern "C" void kernel_launch(void* const* d_in, const int* in_sizes, int n_in,
                              void* d_out, int out_size, void* d_ws, size_t ws_size,
                              hipStream_t stream) {
    const float* x = (const float*)d_in[0];
    float* out = (float*)d_out;
    PositionalEncoding_84095459656362_kernel<<<N4 / 256, 256, 0, stream>>>(x, out);
}